// Round 12
// baseline (182.289 us; speedup 1.0000x reference)
//
#include <hip/hip_runtime.h>
#include <hip/hip_bf16.h>

#define SIZE 4096
#define BT 128             // tile dim (square)
#define BK 64
#define NT (SIZE / BK)     // 64 K-tiles
#define NBG (SIZE / BT)    // 32x32 grid of 128^2 tiles

typedef __bf16 bf16x8 __attribute__((ext_vector_type(8)));
typedef __bf16 bf16x4 __attribute__((ext_vector_type(4)));
typedef float f32x4 __attribute__((ext_vector_type(4)));

__device__ __forceinline__ void gload_lds16(const void* gsrc, void* ldst) {
  __builtin_amdgcn_global_load_lds(
      (const __attribute__((address_space(1))) unsigned int*)gsrc,
      (__attribute__((address_space(3))) unsigned int*)ldst, 16, 0, 0);
}

// ---------------------------------------------------------------------------
// Kernel 1: build L (bf16) — R5's measured-best variant (4-pass, 1024-col
// chunks, 4 cols/thread). fp32 throughout (matches reference underflow).
// ---------------------------------------------------------------------------
__global__ __launch_bounds__(256) void build_L(const float* __restrict__ p,
                                               __bf16* __restrict__ Lb) {
  const int row = blockIdx.x;
  const int tid = threadIdx.x;
  const int lane = tid & 63;
  const int wid = tid >> 6;
  const long base = (long)row * (row - 1) / 2;

  __shared__ float wtot[4];
  float carry = 1.0f;

  for (int j0 = 0; j0 < SIZE; j0 += 1024) {
    const int jb = j0 + tid * 4;
    if (j0 > row) {  // block-uniform: whole chunk past the diagonal
      bf16x4 z = {(__bf16)0.0f, (__bf16)0.0f, (__bf16)0.0f, (__bf16)0.0f};
      *(bf16x4*)&Lb[(size_t)row * SIZE + jb] = z;
      continue;
    }
    float t[4], v[4];
#pragma unroll
    for (int e = 0; e < 4; ++e) {
      const int j = jb + e;
      if (j < row) {
        const float th = tanhf(p[base + j]);
        t[e] = th;
        v[e] = 1.0f - th * th;
      } else {
        t[e] = (j == row) ? 1.0f : 0.0f;  // diag z=1, upper 0
        v[e] = 1.0f;
      }
    }
    const float vt = v[0] * v[1] * v[2] * v[3];
    float incl = vt;
#pragma unroll
    for (int off = 1; off < 64; off <<= 1) {
      float o = __shfl_up(incl, off, 64);
      if (lane >= off) incl *= o;
    }
    if (lane == 63) wtot[wid] = incl;
    __syncthreads();
    float pre = carry;
    for (int w = 0; w < wid; ++w) pre *= wtot[w];
    float excl = __shfl_up(incl, 1, 64);
    if (lane == 0) excl = 1.0f;
    float s = pre * excl;
    bf16x4 out;
#pragma unroll
    for (int e = 0; e < 4; ++e) {
      out[e] = (__bf16)(t[e] * sqrtf(s));
      s *= v[e];
    }
    *(bf16x4*)&Lb[(size_t)row * SIZE + jb] = out;
    const float tot = wtot[0] * wtot[1] * wtot[2] * wtot[3];
    __syncthreads();
    carry *= tot;
  }
}

// ---------------------------------------------------------------------------
// Kernel 2: C = L*L^T — 128x128 tile, 4 waves (2x2, 64x64/wave), BK=64,
// LDS 64KB -> *** 2 co-resident blocks/CU *** (the one axis R5-R10 never
// varied). Mechanism: block A's barrier/lgkm-drain bubbles are filled by
// block B's MFMA issue (m114 co-scheduling; m97-structure's util source).
// Sync skeleton, stage geometry (2 gloads/half-tile), vmcnt ledger
// (prologue 14 loads, gate vmcnt(6)), chunk-XOR swizzle (0 conflicts,
// R4/R5/R11-verified), and m89 C-layout are identical to R5 — only array
// extents and the wave->subtile map shrink.
// ---------------------------------------------------------------------------
__global__ __launch_bounds__(256, 2) void syrk8(const __bf16* __restrict__ Lb,
                                                float* __restrict__ C) {
  // [buf][ab][kh][row][k] : 2*2*2*128*32*2B = 64 KiB
  __shared__ __bf16 lds[2][2][2][128][32];

  // XCD-chunk swizzle (bijective: 1024 % 8 == 0)
  const int bid0 = blockIdx.x;
  const int bid = (bid0 & 7) * 128 + (bid0 >> 3);
  const int bi = bid >> 5, bj = bid & 31;

  const int tid = threadIdx.x;
  const int lane = tid & 63;
  const int wid = tid >> 6;  // 0..3
  const int wm = wid >> 1;   // 0..1 : rows wm*64..+63
  const int wn = wid & 1;    // 0..1 : cols wn*64..+63
  const int r16 = lane & 15;
  const int kg = lane >> 4;
  // swizzled chunk for LDS reads (row bits 1-2 == r16 bits 1-2 always)
  const int rdk = (kg ^ ((r16 >> 1) & 3)) * 8;

  const size_t rowA0 = (size_t)bi * BT;
  const size_t rowB0 = (size_t)bj * BT;

  // staging: wave stages rows wid*32..+31 (2 gloads x 16 rows of 64B)
  const int srow = wid * 32 + (lane >> 2);
  const int schunk = (lane & 3) ^ ((lane >> 3) & 3);  // inverse-swz source

  // half h: tile = h>>2; sub = h&3 -> [A-kh0, B-kh0, A-kh1, B-kh1]
  auto stage = [&](int h) {
    if (h >= 4 * NT) return;
    const int tile = h >> 2, sub = h & 3;
    const int ab = sub & 1, kh = sub >> 1, buf = tile & 1;
    const size_t grow0 = ab ? rowB0 : rowA0;
    const int gk = tile * BK + kh * 32;
    const __bf16* gsrc = Lb + (grow0 + srow) * SIZE + gk + schunk * 8;
    __bf16* base = &lds[buf][ab][kh][0][0];
#pragma unroll
    for (int q = 0; q < 2; ++q)
      gload_lds16(gsrc + (size_t)q * 16 * SIZE, base + (wid * 32 + q * 16) * 32);
  };

  f32x4 acc[4][4] = {};

  // prologue: tile0 (4 halves) + tile1's first 3 halves
  for (int h = 0; h < 7; ++h) stage(h);
  asm volatile("s_waitcnt vmcnt(6)" ::: "memory");  // tile0 landed
  __builtin_amdgcn_s_barrier();

  for (int t = 0; t < NT; ++t) {
    const int buf = t & 1;
    bf16x8 af[2], bf[4];
#pragma unroll
    for (int i = 0; i < 4; ++i) {  // phase: (kh, mh) = (i>>1, i&1)
      const int kh = i >> 1, mh = i & 1;
      if (mh == 0) {  // B-frags for this kh: live across both m-half phases
#pragma unroll
        for (int n = 0; n < 4; ++n)
          bf[n] = *(const bf16x8*)&lds[buf][1][kh][wn * 64 + n * 16 + r16][rdk];
      }
#pragma unroll
      for (int m = 0; m < 2; ++m)
        af[m] = *(const bf16x8*)&lds[buf][0][kh]
                                    [wm * 64 + (mh * 2 + m) * 16 + r16][rdk];

      stage(4 * t + 7 + i);  // 1 half-tile prefetch per phase

      if (i == 3) {  // once per K-tile: gate next tile's data
        if (t == NT - 2)
          asm volatile("s_waitcnt vmcnt(0)" ::: "memory");
        else if (t < NT - 2)
          asm volatile("s_waitcnt vmcnt(6)" ::: "memory");
      }
      __builtin_amdgcn_s_barrier();
      asm volatile("s_waitcnt lgkmcnt(0)" ::: "memory");
      __builtin_amdgcn_sched_barrier(0);
      __builtin_amdgcn_s_setprio(1);
#pragma unroll
      for (int m = 0; m < 2; ++m)
#pragma unroll
        for (int n = 0; n < 4; ++n)
          acc[mh * 2 + m][n] = __builtin_amdgcn_mfma_f32_16x16x32_bf16(
              af[m], bf[n], acc[mh * 2 + m][n], 0, 0, 0);
      __builtin_amdgcn_s_setprio(0);
      __builtin_amdgcn_s_barrier();
    }
  }

  // C/D layout (m89): col = lane&15, row = kg*4 + reg
  float* Cp = C + (rowA0 + wm * 64) * (size_t)SIZE + rowB0 + wn * 64;
#pragma unroll
  for (int m = 0; m < 4; ++m)
#pragma unroll
    for (int n = 0; n < 4; ++n)
#pragma unroll
      for (int j = 0; j < 4; ++j)
        Cp[(size_t)(m * 16 + kg * 4 + j) * SIZE + n * 16 + r16] = acc[m][n][j];
}

// ---------------------------------------------------------------------------
extern "C" void kernel_launch(void* const* d_in, const int* in_sizes, int n_in,
                              void* d_out, int out_size, void* d_ws, size_t ws_size,
                              hipStream_t stream) {
  const float* p = (const float*)d_in[0];
  float* C = (float*)d_out;
  __bf16* Lb = (__bf16*)d_ws;  // 32 MB scratch

  build_L<<<SIZE, 256, 0, stream>>>(p, Lb);
  syrk8<<<NBG * NBG, 256, 0, stream>>>(Lb, C);
}

// Round 13
// 132.296 us; speedup vs baseline: 1.3779x; 1.3779x over previous
//
#include <hip/hip_runtime.h>
#include <hip/hip_bf16.h>

#define SIZE 4096
#define BM 256
#define BK 64
#define NT (SIZE / BK)     // 64 K-tiles
#define NBG (SIZE / BM)    // 16x16 grid of 256^2 tiles

typedef __bf16 bf16x8 __attribute__((ext_vector_type(8)));
typedef __bf16 bf16x4 __attribute__((ext_vector_type(4)));
typedef float f32x4 __attribute__((ext_vector_type(4)));

__device__ __forceinline__ void gload_lds16(const void* gsrc, void* ldst) {
  __builtin_amdgcn_global_load_lds(
      (const __attribute__((address_space(1))) unsigned int*)gsrc,
      (__attribute__((address_space(3))) unsigned int*)ldst, 16, 0, 0);
}

// ---------------------------------------------------------------------------
// Kernel 1: build L (bf16) — R5 measured-best (4-pass, 4 cols/thread).
// fp32 throughout (matches reference underflow).
// ---------------------------------------------------------------------------
__global__ __launch_bounds__(256) void build_L(const float* __restrict__ p,
                                               __bf16* __restrict__ Lb) {
  const int row = blockIdx.x;
  const int tid = threadIdx.x;
  const int lane = tid & 63;
  const int wid = tid >> 6;
  const long base = (long)row * (row - 1) / 2;

  __shared__ float wtot[4];
  float carry = 1.0f;

  for (int j0 = 0; j0 < SIZE; j0 += 1024) {
    const int jb = j0 + tid * 4;
    if (j0 > row) {
      bf16x4 z = {(__bf16)0.0f, (__bf16)0.0f, (__bf16)0.0f, (__bf16)0.0f};
      *(bf16x4*)&Lb[(size_t)row * SIZE + jb] = z;
      continue;
    }
    float t[4], v[4];
#pragma unroll
    for (int e = 0; e < 4; ++e) {
      const int j = jb + e;
      if (j < row) {
        const float th = tanhf(p[base + j]);
        t[e] = th;
        v[e] = 1.0f - th * th;
      } else {
        t[e] = (j == row) ? 1.0f : 0.0f;
        v[e] = 1.0f;
      }
    }
    const float vt = v[0] * v[1] * v[2] * v[3];
    float incl = vt;
#pragma unroll
    for (int off = 1; off < 64; off <<= 1) {
      float o = __shfl_up(incl, off, 64);
      if (lane >= off) incl *= o;
    }
    if (lane == 63) wtot[wid] = incl;
    __syncthreads();
    float pre = carry;
    for (int w = 0; w < wid; ++w) pre *= wtot[w];
    float excl = __shfl_up(incl, 1, 64);
    if (lane == 0) excl = 1.0f;
    float s = pre * excl;
    bf16x4 out;
#pragma unroll
    for (int e = 0; e < 4; ++e) {
      out[e] = (__bf16)(t[e] * sqrtf(s));
      s *= v[e];
    }
    *(bf16x4*)&Lb[(size_t)row * SIZE + jb] = out;
    const float tot = wtot[0] * wtot[1] * wtot[2] * wtot[3];
    __syncthreads();
    carry *= tot;
  }
}

// ---------------------------------------------------------------------------
// Kernel 2: C = L*L^T, 256x256, 8 waves (2Mx4N), BK=64, 16x16x32 MFMA,
// chunk-XOR swizzle (0 conflicts, R4-R11). NEW vs R5: m201's exact phase
// decomposition — each phase = ONE C-QUADRANT x K=64 (16 MFMA), reads
// tapered 16/0/8/0 (two zero-read phases run pure MFMA). Same operand
// register budget as R5 (af 32 + bf0 16 + bf1 16 VGPRs).
// Quadrants: ph0 (m0,n0): af(rows 0-63)xbf0 | ph1 (m0,n1): af x bf1
//            ph2 (m1,n0): af(rows 64-127)xbf0 | ph3 (m1,n1): af x bf1
// Stage/hazard ledger (stage of region R for t+2 (same buf) must follow
// last confirmed read of R in tile t):
//   B-kh0/B-kh1 last read ph0 (lgkm(0)+barrier) -> stage B0@ph1, B1@ph2 OK
//   A-kh0/A-kh1 last read ph2 (lgkm(0)+barrier) -> stage A0@ph3 OK
//   ph0 stages A1(t+1) -> nbuf (last read: tile t-1 ph2, long confirmed)
// vmcnt ledger: prologue 7 halves {t0 all, t1 B0,B1,A0} = 14 loads,
// vmcnt(6) = t0 landed. Steady gate @ph3: 6 + 8 issued = 14 -> vmcnt(6)
// drains 8 oldest = t+1 {B0,B1,A0 (prologue) + A1 (ph0)} exactly. Tail:
// t==NT-2 -> vmcnt(0); stage guards t<NT-1 (ph0) / t<NT-2 (ph1-3).
// ---------------------------------------------------------------------------
__global__ __launch_bounds__(512, 1) void syrk8(const __bf16* __restrict__ Lb,
                                                float* __restrict__ C) {
  __shared__ __bf16 lds[2][2][2][256][32];  // [buf][ab][kh][row][k] 128 KiB

  const int bid0 = blockIdx.x;
  const int bid = (bid0 & 7) * 32 + (bid0 >> 3);  // bijective XCD chunking
  const int bi = bid >> 4, bj = bid & 15;

  const int tid = threadIdx.x;
  const int lane = tid & 63;
  const int wid = tid >> 6;  // 0..7
  const int wm = wid >> 2;   // 0..1 : rows wm*128..+127
  const int wn = wid & 3;    // 0..3 : cols wn*64..+63
  const int r16 = lane & 15;
  const int kg = lane >> 4;
  const int rdk = (kg ^ ((r16 >> 1) & 3)) * 8;  // swizzled read chunk

  const size_t rowA0 = (size_t)bi * 256;
  const size_t rowB0 = (size_t)bj * 256;

  const int srow = wid * 32 + (lane >> 2);
  const int schunk = (lane & 3) ^ ((lane >> 3) & 3);  // inverse-swz source

  // stage half (tile, sub): sub 0=A-kh0, 1=B-kh0, 2=A-kh1, 3=B-kh1
  auto stage = [&](int tile, int sub) {
    const int ab = sub & 1, kh = sub >> 1, b = tile & 1;
    const size_t grow0 = ab ? rowB0 : rowA0;
    const int gk = tile * BK + kh * 32;
    const __bf16* gsrc = Lb + (grow0 + srow) * SIZE + gk + schunk * 8;
    __bf16* base = &lds[b][ab][kh][0][0];
    gload_lds16(gsrc, base + (wid * 32) * 32);
    gload_lds16(gsrc + (size_t)16 * SIZE, base + (wid * 32 + 16) * 32);
  };

  f32x4 acc[8][4] = {};
  bf16x8 af[4][2], bf0[2][2], bf1[2][2];  // [frag][kh]

#define MMA(AF, BF, MOFF, NOFF)                                            \
  {                                                                        \
    __builtin_amdgcn_s_setprio(1);                                         \
    _Pragma("unroll") for (int h = 0; h < 2; ++h)                          \
        _Pragma("unroll") for (int m = 0; m < 4; ++m)                      \
            _Pragma("unroll") for (int n = 0; n < 2; ++n)                  \
                acc[(MOFF) + m][(NOFF) + n] =                              \
        __builtin_amdgcn_mfma_f32_16x16x32_bf16(AF[m][h], BF[n][h],        \
                                                acc[(MOFF) + m][(NOFF) + n],\
                                                0, 0, 0);                  \
    __builtin_amdgcn_s_setprio(0);                                         \
  }

  // prologue: t0 {A0,B0,A1,B1} + t1 {B0,B1,A0}
  stage(0, 0); stage(0, 1); stage(0, 2); stage(0, 3);
  stage(1, 1); stage(1, 3); stage(1, 0);
  asm volatile("s_waitcnt vmcnt(6)" ::: "memory");  // t0 landed
  __builtin_amdgcn_s_barrier();

  for (int t = 0; t < NT; ++t) {
    const int buf = t & 1;
    // ---- ph0: reads af(rows 0-63)+bf0+bf1 (16); stage A1(t+1)->nbuf ----
#pragma unroll
    for (int m = 0; m < 4; ++m)
#pragma unroll
      for (int h = 0; h < 2; ++h)
        af[m][h] = *(const bf16x8*)&lds[buf][0][h][wm * 128 + m * 16 + r16][rdk];
#pragma unroll
    for (int n = 0; n < 2; ++n)
#pragma unroll
      for (int h = 0; h < 2; ++h) {
        bf0[n][h] = *(const bf16x8*)&lds[buf][1][h][wn * 64 + n * 16 + r16][rdk];
        bf1[n][h] =
            *(const bf16x8*)&lds[buf][1][h][wn * 64 + 32 + n * 16 + r16][rdk];
      }
    if (t < NT - 1) stage(t + 1, 2);
    asm volatile("s_waitcnt lgkmcnt(8)" ::: "memory");  // m201 pacing hint
    __builtin_amdgcn_s_barrier();
    asm volatile("s_waitcnt lgkmcnt(0)" ::: "memory");
    __builtin_amdgcn_sched_barrier(0);
    MMA(af, bf0, 0, 0);
    __builtin_amdgcn_s_barrier();
    // ---- ph1: 0 reads; stage B0(t+2); MFMA af x bf1 ----
    if (t < NT - 2) stage(t + 2, 1);
    __builtin_amdgcn_s_barrier();
    MMA(af, bf1, 0, 2);
    __builtin_amdgcn_s_barrier();
    // ---- ph2: reads af(rows 64-127) (8); stage B1(t+2); MFMA af x bf0 ----
#pragma unroll
    for (int m = 0; m < 4; ++m)
#pragma unroll
      for (int h = 0; h < 2; ++h)
        af[m][h] =
            *(const bf16x8*)&lds[buf][0][h][wm * 128 + 64 + m * 16 + r16][rdk];
    if (t < NT - 2) stage(t + 2, 3);
    __builtin_amdgcn_s_barrier();
    asm volatile("s_waitcnt lgkmcnt(0)" ::: "memory");
    __builtin_amdgcn_sched_barrier(0);
    MMA(af, bf0, 4, 0);
    __builtin_amdgcn_s_barrier();
    // ---- ph3: 0 reads; stage A0(t+2) + gate; MFMA af x bf1 ----
    if (t < NT - 2) {
      stage(t + 2, 0);
      asm volatile("s_waitcnt vmcnt(6)" ::: "memory");
    } else if (t == NT - 2) {
      asm volatile("s_waitcnt vmcnt(0)" ::: "memory");
    }
    __builtin_amdgcn_s_barrier();
    MMA(af, bf1, 4, 2);
    __builtin_amdgcn_s_barrier();
  }

  // C/D layout (m89): col = lane&15, row = kg*4 + reg
  float* Cp = C + (rowA0 + wm * 128) * (size_t)SIZE + rowB0 + wn * 64;
#pragma unroll
  for (int m = 0; m < 8; ++m)
#pragma unroll
    for (int n = 0; n < 4; ++n)
#pragma unroll
      for (int j = 0; j < 4; ++j)
        Cp[(size_t)(m * 16 + kg * 4 + j) * SIZE + n * 16 + r16] = acc[m][n][j];
#undef MMA
}

// ---------------------------------------------------------------------------
extern "C" void kernel_launch(void* const* d_in, const int* in_sizes, int n_in,
                              void* d_out, int out_size, void* d_ws, size_t ws_size,
                              hipStream_t stream) {
  const float* p = (const float*)d_in[0];
  float* C = (float*)d_out;
  __bf16* Lb = (__bf16*)d_ws;  // 32 MB scratch

  build_L<<<SIZE, 256, 0, stream>>>(p, Lb);
  syrk8<<<NBG * NBG, 512, 0, stream>>>(Lb, C);
}